// Round 4
// baseline (895.313 us; speedup 1.0000x reference)
//
#include <hip/hip_runtime.h>

// GCN encoder: 3 layers of  out = Ddst^-1/2 * A * Dsrc^-1/2 * X * W + b
// N=100000, E=1600000, dims 128->128->128->64, all fp32.
//
// Round 3: fuse SpMM-gather + GEMM for layers 0/1.
//  - block owns 64 dst rows; gather phase: 8 lanes/node, 4x float4 fp32
//    register accumulate over CSR in-edges, ndst folded, -> LDS sX[64][128]
//  - GEMM phase: W staged in 4x 32-row LDS chunks (16 KB), 512 thr,
//    each thread 4x4 outputs; bias + optional nsrc output-scale epilogue
//  - 48 KB LDS -> 3 blocks/CU: gather-phase blocks overlap GEMM-phase blocks
//  - kills agg round-trip (102 MB/layer) and 2 dispatches
//  - layer 2 unchanged: y2 = nsrc*(h@W2) dense, then final fused gather+scale+bias

#define DK 128

// ---------- degree count (int atomics) ----------
__global__ __launch_bounds__(256) void deg_kernel(const int* __restrict__ src,
                                                  const int* __restrict__ dst,
                                                  int* __restrict__ deg_out,
                                                  int* __restrict__ deg_in, int E) {
    int e = blockIdx.x * blockDim.x + threadIdx.x;
    if (e < E) {
        atomicAdd(&deg_out[src[e]], 1);
        atomicAdd(&deg_in[dst[e]], 1);
    }
}

__global__ __launch_bounds__(256) void norm_kernel(const int* __restrict__ deg_out,
                                                   const int* __restrict__ deg_in,
                                                   float* __restrict__ nsrc,
                                                   float* __restrict__ ndst, int n) {
    int i = blockIdx.x * blockDim.x + threadIdx.x;
    if (i < n) {
        nsrc[i] = rsqrtf(fmaxf((float)deg_out[i], 1.0f));
        ndst[i] = rsqrtf(fmaxf((float)deg_in[i], 1.0f));
    }
}

// ---------- phase A: per-chunk (2048 elems) local inclusive scan ----------
__global__ __launch_bounds__(256) void scanA(const int* __restrict__ deg,
                                             int* __restrict__ rp,
                                             int* __restrict__ csum, int n) {
    __shared__ int wsum[4];
    const int tid = threadIdx.x;
    const int base = blockIdx.x * 2048 + tid * 8;
    int v[8];
    int s = 0;
#pragma unroll
    for (int j = 0; j < 8; ++j) {
        int i = base + j;
        v[j] = (i < n) ? deg[i] : 0;
        s += v[j];
    }
    int run = 0;
#pragma unroll
    for (int j = 0; j < 8; ++j) { run += v[j]; v[j] = run; }
    const int lane = tid & 63;
    const int w = tid >> 6;
    int sc = s;
#pragma unroll
    for (int off = 1; off < 64; off <<= 1) {
        int t = __shfl_up(sc, off, 64);
        if (lane >= off) sc += t;
    }
    if (lane == 63) wsum[w] = sc;
    __syncthreads();
    int woff = 0;
    for (int k = 0; k < w; ++k) woff += wsum[k];
    const int texcl = woff + sc - s;
#pragma unroll
    for (int j = 0; j < 8; ++j) {
        int i = base + j;
        if (i < n) rp[i + 1] = texcl + v[j];
    }
    if (tid == 0) csum[blockIdx.x] = wsum[0] + wsum[1] + wsum[2] + wsum[3];
}

// ---------- phase B: scan chunk sums (G <= 256) ----------
__global__ __launch_bounds__(256) void scanB(const int* __restrict__ csum,
                                             int* __restrict__ coffs, int g) {
    __shared__ int wsum[4];
    const int tid = threadIdx.x;
    int s = (tid < g) ? csum[tid] : 0;
    const int lane = tid & 63;
    const int w = tid >> 6;
    int sc = s;
#pragma unroll
    for (int off = 1; off < 64; off <<= 1) {
        int t = __shfl_up(sc, off, 64);
        if (lane >= off) sc += t;
    }
    if (lane == 63) wsum[w] = sc;
    __syncthreads();
    int woff = 0;
    for (int k = 0; k < w; ++k) woff += wsum[k];
    if (tid < g) coffs[tid] = woff + sc - s;
}

// ---------- phase C: add chunk offsets, derive cursor ----------
__global__ __launch_bounds__(256) void scanC(const int* __restrict__ deg,
                                             const int* __restrict__ coffs,
                                             int* __restrict__ rp,
                                             int* __restrict__ cur, int n) {
    const int tid = threadIdx.x;
    const int base = blockIdx.x * 2048 + tid * 8;
    const int add = coffs[blockIdx.x];
#pragma unroll
    for (int j = 0; j < 8; ++j) {
        int i = base + j;
        if (i < n) {
            int r = rp[i + 1] + add;
            rp[i + 1] = r;
            cur[i] = r - deg[i];
        }
    }
    if (blockIdx.x == 0 && tid == 0) rp[0] = 0;
}

// ---------- scatter src indices into CSR slots ----------
__global__ __launch_bounds__(256) void fill_kernel(const int* __restrict__ src,
                                                   const int* __restrict__ dst,
                                                   int* __restrict__ cur,
                                                   int* __restrict__ eidx, int E) {
    int e = blockIdx.x * blockDim.x + threadIdx.x;
    if (e < E) {
        int pos = atomicAdd(&cur[dst[e]], 1);
        eidx[pos] = src[e];
    }
}

// ---------- fused: Y[r,:] = oscale? * ( (ndst[r] * sum_{e in in(r)} x[src,:]*nsrc?[src]) @ W + bias ) ----------
// block = 64 dst rows, 512 threads. LDS: sX 32KB + sW 16KB = 48KB (3 blocks/CU).
template <bool NSRC, bool OSCALE>
__global__ __launch_bounds__(512) void fused_spmm_gemm(
    const float* __restrict__ x, const float* __restrict__ nsrc,
    const int* __restrict__ eidx, const int* __restrict__ rp,
    const float* __restrict__ ndst, const float* __restrict__ W,
    const float* __restrict__ bias, const float* __restrict__ oscale,
    float* __restrict__ Y, int n) {
    constexpr int K = DK;       // 128
    constexpr int C = DK;       // 128
    constexpr int BM = 64;
    constexpr int WCH = 32;     // W chunk rows

    __shared__ float sX[BM][K];     // 32 KB
    __shared__ float sW[WCH][C];    // 16 KB

    const int tid = threadIdx.x;

    // ---- gather phase: 8 lanes per node, 16 floats/lane ----
    {
        const int node_l = tid >> 3;          // 0..63
        const int lane = tid & 7;             // 0..7
        const int node = blockIdx.x * BM + node_l;
        float4 a0 = make_float4(0.f, 0.f, 0.f, 0.f);
        float4 a1 = a0, a2 = a0, a3 = a0;
        if (node < n) {
            const int beg = rp[node];
            const int end = rp[node + 1];
#pragma unroll 2
            for (int e = beg; e < end; ++e) {
                int s = eidx[e];
                const float* row = x + (size_t)s * K + lane * 16;
                float4 v0 = *(const float4*)(row);
                float4 v1 = *(const float4*)(row + 4);
                float4 v2 = *(const float4*)(row + 8);
                float4 v3 = *(const float4*)(row + 12);
                if (NSRC) {
                    float ns = nsrc[s];
                    a0.x += v0.x * ns; a0.y += v0.y * ns; a0.z += v0.z * ns; a0.w += v0.w * ns;
                    a1.x += v1.x * ns; a1.y += v1.y * ns; a1.z += v1.z * ns; a1.w += v1.w * ns;
                    a2.x += v2.x * ns; a2.y += v2.y * ns; a2.z += v2.z * ns; a2.w += v2.w * ns;
                    a3.x += v3.x * ns; a3.y += v3.y * ns; a3.z += v3.z * ns; a3.w += v3.w * ns;
                } else {
                    a0.x += v0.x; a0.y += v0.y; a0.z += v0.z; a0.w += v0.w;
                    a1.x += v1.x; a1.y += v1.y; a1.z += v1.z; a1.w += v1.w;
                    a2.x += v2.x; a2.y += v2.y; a2.z += v2.z; a2.w += v2.w;
                    a3.x += v3.x; a3.y += v3.y; a3.z += v3.z; a3.w += v3.w;
                }
            }
            const float sd = ndst[node];
            a0.x *= sd; a0.y *= sd; a0.z *= sd; a0.w *= sd;
            a1.x *= sd; a1.y *= sd; a1.z *= sd; a1.w *= sd;
            a2.x *= sd; a2.y *= sd; a2.z *= sd; a2.w *= sd;
            a3.x *= sd; a3.y *= sd; a3.z *= sd; a3.w *= sd;
        }
        float* p = &sX[node_l][lane * 16];
        *(float4*)(p + 0) = a0;
        *(float4*)(p + 4) = a1;
        *(float4*)(p + 8) = a2;
        *(float4*)(p + 12) = a3;
    }
    __syncthreads();

    // ---- GEMM phase: (sX 64x128) @ (W 128x128) ----
    const int tc = tid & 31;        // col group (x4)
    const int tr = tid >> 5;        // 0..15
    const int c0 = tc * 4;
    const int r0 = tr * 4;          // 4 rows/thread

    float acc[4][4];
#pragma unroll
    for (int i = 0; i < 4; ++i)
#pragma unroll
        for (int j = 0; j < 4; ++j) acc[i][j] = 0.f;

    for (int ch = 0; ch < K / WCH; ++ch) {
        if (ch > 0) __syncthreads();
        // stage W rows [ch*32, ch*32+32) : 4096 floats = 1024 float4 = 2/thread
        {
            const float4* Wv = (const float4*)(W + (size_t)ch * WCH * C);
#pragma unroll
            for (int t = 0; t < 2; ++t) {
                int i = tid + t * 512;
                int k = i >> 5;          // /(C/4)=32
                int cc = i & 31;
                *(float4*)&sW[k][cc * 4] = Wv[i];
            }
        }
        __syncthreads();
#pragma unroll
        for (int kk = 0; kk < WCH; kk += 4) {
            float wv[4][4];
#pragma unroll
            for (int j = 0; j < 4; ++j) {
                float4 t = *(const float4*)&sW[kk + j][c0];
                wv[j][0] = t.x; wv[j][1] = t.y; wv[j][2] = t.z; wv[j][3] = t.w;
            }
#pragma unroll
            for (int i = 0; i < 4; ++i) {
                float4 xv = *(const float4*)&sX[r0 + i][ch * WCH + kk];
#pragma unroll
                for (int j = 0; j < 4; ++j) {
                    acc[i][j] += xv.x * wv[0][j] + xv.y * wv[1][j] +
                                 xv.z * wv[2][j] + xv.w * wv[3][j];
                }
            }
        }
    }

    float4 bv = ((const float4*)bias)[tc];
#pragma unroll
    for (int i = 0; i < 4; ++i) {
        int gr = blockIdx.x * BM + r0 + i;
        if (gr < n) {
            float os = OSCALE ? oscale[gr] : 1.0f;
            float4 o = make_float4((acc[i][0] + bv.x) * os, (acc[i][1] + bv.y) * os,
                                   (acc[i][2] + bv.z) * os, (acc[i][3] + bv.w) * os);
            *(float4*)(Y + (size_t)gr * C + c0) = o;
        }
    }
}

// ---------- SpMM gather (final layer, D=64): out = ndst*(A*y2) + b2 ----------
template <int D, bool NSRC, bool FINAL>
__global__ __launch_bounds__(256) void spmm_gather(const float* __restrict__ x,
                                                   const float* __restrict__ nsrc,
                                                   const int* __restrict__ eidx,
                                                   const int* __restrict__ rp,
                                                   const float* __restrict__ ndst,
                                                   const float* __restrict__ bias,
                                                   float* __restrict__ out, int n) {
    constexpr int TPN = D / 8;
    constexpr int NPB = 256 / TPN;
    const int node = blockIdx.x * NPB + threadIdx.x / TPN;
    const int lane = threadIdx.x % TPN;
    if (node >= n) return;
    const int beg = rp[node];
    const int end = rp[node + 1];
    float4 a0 = make_float4(0.f, 0.f, 0.f, 0.f);
    float4 a1 = make_float4(0.f, 0.f, 0.f, 0.f);
#pragma unroll 4
    for (int e = beg; e < end; ++e) {
        int s = eidx[e];
        const float* row = x + (size_t)s * D + lane * 8;
        float4 v0 = *(const float4*)(row);
        float4 v1 = *(const float4*)(row + 4);
        if (NSRC) {
            float ns = nsrc[s];
            a0.x += v0.x * ns; a0.y += v0.y * ns; a0.z += v0.z * ns; a0.w += v0.w * ns;
            a1.x += v1.x * ns; a1.y += v1.y * ns; a1.z += v1.z * ns; a1.w += v1.w * ns;
        } else {
            a0.x += v0.x; a0.y += v0.y; a0.z += v0.z; a0.w += v0.w;
            a1.x += v1.x; a1.y += v1.y; a1.z += v1.z; a1.w += v1.w;
        }
    }
    if (FINAL) {
        float sd = ndst[node];
        float4 b0 = *(const float4*)(bias + lane * 8);
        float4 b1 = *(const float4*)(bias + lane * 8 + 4);
        a0.x = a0.x * sd + b0.x; a0.y = a0.y * sd + b0.y;
        a0.z = a0.z * sd + b0.z; a0.w = a0.w * sd + b0.w;
        a1.x = a1.x * sd + b1.x; a1.y = a1.y * sd + b1.y;
        a1.z = a1.z * sd + b1.z; a1.w = a1.w * sd + b1.w;
    }
    float* o = out + (size_t)node * D + lane * 8;
    *(float4*)(o) = a0;
    *(float4*)(o + 4) = a1;
}

// ---------- dense GEMM (layer-2 y2 = nsrc*(h@W2)) ----------
template <int C, bool ISCALE, bool OSCALE, bool BIAS>
__global__ __launch_bounds__(512) void gemm_kernel(const float* __restrict__ X,
                                                   const float* __restrict__ W,
                                                   const float* __restrict__ bias,
                                                   const float* __restrict__ iscale,
                                                   const float* __restrict__ oscale,
                                                   float* __restrict__ Y, int n) {
    constexpr int K = DK;
    constexpr int BM = 128;
    constexpr int KP = K + 4;
    constexpr int COLT = C / 4;
    constexpr int ROWT = 512 / COLT;
    constexpr int RPT = BM / ROWT;

    __shared__ float sW[K][C];
    __shared__ float sX[BM][KP];

    const int tid = threadIdx.x;
    const int row0 = blockIdx.x * BM;

    for (int i = tid; i < K * C / 4; i += 512) {
        float4 w = ((const float4*)W)[i];
        int k = i / (C / 4);
        int cc = i % (C / 4);
        *(float4*)&sW[k][cc * 4] = w;
    }
    for (int i = tid; i < BM * (K / 4); i += 512) {
        int r = i / (K / 4);
        int kc = i % (K / 4);
        int gr = row0 + r;
        float4 v = make_float4(0.f, 0.f, 0.f, 0.f);
        if (gr < n) {
            v = *(const float4*)(X + (size_t)gr * K + kc * 4);
            if (ISCALE) {
                float s = iscale[gr];
                v.x *= s; v.y *= s; v.z *= s; v.w *= s;
            }
        }
        *(float4*)&sX[r][kc * 4] = v;
    }
    __syncthreads();

    const int tc = tid % COLT;
    const int tr = tid / COLT;
    const int c0 = tc * 4;
    const int r0 = tr * RPT;

    float acc[RPT][4];
#pragma unroll
    for (int i = 0; i < RPT; ++i)
#pragma unroll
        for (int j = 0; j < 4; ++j) acc[i][j] = 0.f;

    for (int k = 0; k < K; k += 4) {
        float wv[4][4];
#pragma unroll
        for (int j = 0; j < 4; ++j) {
            float4 t = *(const float4*)&sW[k + j][c0];
            wv[j][0] = t.x; wv[j][1] = t.y; wv[j][2] = t.z; wv[j][3] = t.w;
        }
#pragma unroll
        for (int i = 0; i < RPT; ++i) {
            float4 xv = *(const float4*)&sX[r0 + i][k];
#pragma unroll
            for (int j = 0; j < 4; ++j) {
                acc[i][j] += xv.x * wv[0][j] + xv.y * wv[1][j] +
                             xv.z * wv[2][j] + xv.w * wv[3][j];
            }
        }
    }

    float bv[4] = {0.f, 0.f, 0.f, 0.f};
    if (BIAS) {
        float4 t = ((const float4*)bias)[tc];
        bv[0] = t.x; bv[1] = t.y; bv[2] = t.z; bv[3] = t.w;
    }
#pragma unroll
    for (int i = 0; i < RPT; ++i) {
        int gr = row0 + r0 + i;
        if (gr < n) {
            float os = OSCALE ? oscale[gr] : 1.0f;
            float4 o = make_float4((acc[i][0] + bv[0]) * os, (acc[i][1] + bv[1]) * os,
                                   (acc[i][2] + bv[2]) * os, (acc[i][3] + bv[3]) * os);
            *(float4*)(Y + (size_t)gr * C + c0) = o;
        }
    }
}

static inline int cdiv(long long a, long long b) { return (int)((a + b - 1) / b); }

extern "C" void kernel_launch(void* const* d_in, const int* in_sizes, int n_in,
                              void* d_out, int out_size, void* d_ws, size_t ws_size,
                              hipStream_t stream) {
    const float* feat = (const float*)d_in[0];
    const float* W0   = (const float*)d_in[1];
    const float* b0   = (const float*)d_in[2];
    const float* W1   = (const float*)d_in[3];
    const float* b1   = (const float*)d_in[4];
    const float* W2   = (const float*)d_in[5];
    const float* b2   = (const float*)d_in[6];
    const int*   src  = (const int*)d_in[7];
    const int*   dst  = (const int*)d_in[8];

    const int N = in_sizes[0] / DK;
    const int E = in_sizes[7];

    // ws: nsrc[N] ndst[N] rp[N+1] csum[256] coffs[256] eidx[E] h0[N*128] h1[N*128]
    //     deg_out/deg_in/cur alias h0 (dead before layer 0 output)
    //     y2 aliases h0 (dead after layer-1 gather)
    float* ws      = (float*)d_ws;
    float* nsrc    = ws;
    float* ndst    = ws + N;
    int*   rp      = (int*)(ws + 2 * (size_t)N);
    int*   csum    = rp + (N + 1);
    int*   coffs   = csum + 256;
    int*   eidx    = coffs + 256;
    size_t aoff    = (size_t)(3 * (size_t)N + 513 + E + 3) & ~(size_t)3;
    float* h0      = ws + aoff;                       // [N*128]
    float* h1      = h0 + (size_t)N * 128;            // [N*128]
    int*   deg_out = (int*)h0;
    int*   deg_in  = deg_out + N;
    int*   cur     = deg_in + N;
    float* y2      = h0;                              // [N*64]

    const int chunks = cdiv(N, 2048);

    // ---- CSR build + norms ----
    hipMemsetAsync(deg_out, 0, 2 * (size_t)N * sizeof(int), stream);
    deg_kernel<<<cdiv(E, 256), 256, 0, stream>>>(src, dst, deg_out, deg_in, E);
    norm_kernel<<<cdiv(N, 256), 256, 0, stream>>>(deg_out, deg_in, nsrc, ndst, N);
    scanA<<<chunks, 256, 0, stream>>>(deg_in, rp, csum, N);
    scanB<<<1, 256, 0, stream>>>(csum, coffs, chunks);
    scanC<<<chunks, 256, 0, stream>>>(deg_in, coffs, rp, cur, N);
    fill_kernel<<<cdiv(E, 256), 256, 0, stream>>>(src, dst, cur, eidx, E);

    const int fb = cdiv(N, 64);

    // ---- layer 0: h0 = nsrc * ( (ndst * A*(nsrc*feat)) @ W0 + b0 ) ----
    fused_spmm_gemm<true, true><<<fb, 512, 0, stream>>>(
        feat, nsrc, eidx, rp, ndst, W0, b0, nsrc, h0, N);

    // ---- layer 1: h1 = (ndst * A*h0) @ W1 + b1 ----
    fused_spmm_gemm<false, false><<<fb, 512, 0, stream>>>(
        h0, nullptr, eidx, rp, ndst, W1, b1, nullptr, h1, N);

    // ---- layer 2: y2 = nsrc*(h1@W2); out = ndst*(A*y2) + b2 ----
    gemm_kernel<64, false, true, false><<<cdiv(N, 128), 512, 0, stream>>>(
        h1, W2, nullptr, nullptr, nsrc, y2, N);
    spmm_gather<64, false, true><<<cdiv(N, 32), 256, 0, stream>>>(
        y2, nullptr, eidx, rp, ndst, b2, (float*)d_out, N);
}

// Round 5
// 707.180 us; speedup vs baseline: 1.2660x; 1.2660x over previous
//
#include <hip/hip_runtime.h>
#include <hip/hip_fp16.h>

// GCN encoder: 3 layers of  out = Ddst^-1/2 * A * Dsrc^-1/2 * X * W + b
// N=100000, E=1600000, dims 128->128->128->64, all fp32 in/out.
//
// Round 4: round-2 unfused structure + fp16 gather operands (gather is
// memory-system-throughput bound: round-3 fusion failed on occupancy, and
// round-2/3 showed MLP-insensitivity; halving bytes is the remaining lever).
//  - feat16 = fp16(nsrc*feat) via one convert pass
//  - gemm epilogues emit fp16 where the consumer is a gather:
//      h0_16 = fp16( nsrc*((ndst*agg0)@W0 + b0) )
//      y2_16 = fp16( nsrc*(h1@W2) )
//  - h1 stays fp32 (consumed linearly by gemm64 only)
//  - gathers: f16x8 loads (16B/lane), fp32 accumulate, fp32 out
//  - final gather fuses ndst scale + b2 and writes d_out

#define DK 128

typedef _Float16 f16x8 __attribute__((ext_vector_type(8)));
typedef _Float16 f16x4 __attribute__((ext_vector_type(4)));

// ---------- degree count (int atomics) ----------
__global__ __launch_bounds__(256) void deg_kernel(const int* __restrict__ src,
                                                  const int* __restrict__ dst,
                                                  int* __restrict__ deg_out,
                                                  int* __restrict__ deg_in, int E) {
    int e = blockIdx.x * blockDim.x + threadIdx.x;
    if (e < E) {
        atomicAdd(&deg_out[src[e]], 1);
        atomicAdd(&deg_in[dst[e]], 1);
    }
}

__global__ __launch_bounds__(256) void norm_kernel(const int* __restrict__ deg_out,
                                                   const int* __restrict__ deg_in,
                                                   float* __restrict__ nsrc,
                                                   float* __restrict__ ndst, int n) {
    int i = blockIdx.x * blockDim.x + threadIdx.x;
    if (i < n) {
        nsrc[i] = rsqrtf(fmaxf((float)deg_out[i], 1.0f));
        ndst[i] = rsqrtf(fmaxf((float)deg_in[i], 1.0f));
    }
}

// ---------- 3-phase prefix scan ----------
__global__ __launch_bounds__(256) void scanA(const int* __restrict__ deg,
                                             int* __restrict__ rp,
                                             int* __restrict__ csum, int n) {
    __shared__ int wsum[4];
    const int tid = threadIdx.x;
    const int base = blockIdx.x * 2048 + tid * 8;
    int v[8];
    int s = 0;
#pragma unroll
    for (int j = 0; j < 8; ++j) {
        int i = base + j;
        v[j] = (i < n) ? deg[i] : 0;
        s += v[j];
    }
    int run = 0;
#pragma unroll
    for (int j = 0; j < 8; ++j) { run += v[j]; v[j] = run; }
    const int lane = tid & 63;
    const int w = tid >> 6;
    int sc = s;
#pragma unroll
    for (int off = 1; off < 64; off <<= 1) {
        int t = __shfl_up(sc, off, 64);
        if (lane >= off) sc += t;
    }
    if (lane == 63) wsum[w] = sc;
    __syncthreads();
    int woff = 0;
    for (int k = 0; k < w; ++k) woff += wsum[k];
    const int texcl = woff + sc - s;
#pragma unroll
    for (int j = 0; j < 8; ++j) {
        int i = base + j;
        if (i < n) rp[i + 1] = texcl + v[j];
    }
    if (tid == 0) csum[blockIdx.x] = wsum[0] + wsum[1] + wsum[2] + wsum[3];
}

__global__ __launch_bounds__(256) void scanB(const int* __restrict__ csum,
                                             int* __restrict__ coffs, int g) {
    __shared__ int wsum[4];
    const int tid = threadIdx.x;
    int s = (tid < g) ? csum[tid] : 0;
    const int lane = tid & 63;
    const int w = tid >> 6;
    int sc = s;
#pragma unroll
    for (int off = 1; off < 64; off <<= 1) {
        int t = __shfl_up(sc, off, 64);
        if (lane >= off) sc += t;
    }
    if (lane == 63) wsum[w] = sc;
    __syncthreads();
    int woff = 0;
    for (int k = 0; k < w; ++k) woff += wsum[k];
    if (tid < g) coffs[tid] = woff + sc - s;
}

__global__ __launch_bounds__(256) void scanC(const int* __restrict__ deg,
                                             const int* __restrict__ coffs,
                                             int* __restrict__ rp,
                                             int* __restrict__ cur, int n) {
    const int tid = threadIdx.x;
    const int base = blockIdx.x * 2048 + tid * 8;
    const int add = coffs[blockIdx.x];
#pragma unroll
    for (int j = 0; j < 8; ++j) {
        int i = base + j;
        if (i < n) {
            int r = rp[i + 1] + add;
            rp[i + 1] = r;
            cur[i] = r - deg[i];
        }
    }
    if (blockIdx.x == 0 && tid == 0) rp[0] = 0;
}

// ---------- scatter src indices into CSR slots ----------
__global__ __launch_bounds__(256) void fill_kernel(const int* __restrict__ src,
                                                   const int* __restrict__ dst,
                                                   int* __restrict__ cur,
                                                   int* __restrict__ eidx, int E) {
    int e = blockIdx.x * blockDim.x + threadIdx.x;
    if (e < E) {
        int pos = atomicAdd(&cur[dst[e]], 1);
        eidx[pos] = src[e];
    }
}

// ---------- convert + row-scale: o[r,:] = fp16(x[r,:] * scale[r]), D=128 ----------
__global__ __launch_bounds__(256) void cvt_scale_kernel(const float* __restrict__ x,
                                                        const float* __restrict__ scale,
                                                        _Float16* __restrict__ o, int n8) {
    int i = blockIdx.x * blockDim.x + threadIdx.x;   // one per 8 elements
    if (i >= n8) return;
    int row = i >> 4;                                // 16 chunks per 128-wide row
    float s = scale[row];
    const float4 v0 = *(const float4*)(x + (size_t)i * 8);
    const float4 v1 = *(const float4*)(x + (size_t)i * 8 + 4);
    f16x8 r;
    r[0] = (_Float16)(v0.x * s); r[1] = (_Float16)(v0.y * s);
    r[2] = (_Float16)(v0.z * s); r[3] = (_Float16)(v0.w * s);
    r[4] = (_Float16)(v1.x * s); r[5] = (_Float16)(v1.y * s);
    r[6] = (_Float16)(v1.z * s); r[7] = (_Float16)(v1.w * s);
    *(f16x8*)(o + (size_t)i * 8) = r;
}

// ---------- SpMM gather over fp16 rows ----------
// out[r,:] = sum_{e in in(r)} x16[src_e,:]        (inputs pre-scaled by nsrc)
// FINAL: out[r,:] = (sum ...) * ndst[r] + bias
template <int D, bool FINAL>
__global__ __launch_bounds__(256) void spmm_gather16(const _Float16* __restrict__ x,
                                                     const int* __restrict__ eidx,
                                                     const int* __restrict__ rp,
                                                     const float* __restrict__ ndst,
                                                     const float* __restrict__ bias,
                                                     float* __restrict__ out, int n) {
    constexpr int TPN = D / 8;        // lanes per node (16 for D=128, 8 for D=64)
    constexpr int NPB = 256 / TPN;
    const int node = blockIdx.x * NPB + threadIdx.x / TPN;
    const int lane = threadIdx.x % TPN;
    if (node >= n) return;
    const int beg = rp[node];
    const int end = rp[node + 1];
    float acc[8] = {0.f, 0.f, 0.f, 0.f, 0.f, 0.f, 0.f, 0.f};
#pragma unroll 2
    for (int e = beg; e < end; ++e) {
        int s = eidx[e];
        f16x8 v = *(const f16x8*)(x + (size_t)s * D + lane * 8);
#pragma unroll
        for (int j = 0; j < 8; ++j) acc[j] += (float)v[j];
    }
    float* o = out + (size_t)node * D + lane * 8;
    if (FINAL) {
        float sd = ndst[node];
        float4 b0 = *(const float4*)(bias + lane * 8);
        float4 b1 = *(const float4*)(bias + lane * 8 + 4);
        float4 o0 = make_float4(acc[0] * sd + b0.x, acc[1] * sd + b0.y,
                                acc[2] * sd + b0.z, acc[3] * sd + b0.w);
        float4 o1 = make_float4(acc[4] * sd + b1.x, acc[5] * sd + b1.y,
                                acc[6] * sd + b1.z, acc[7] * sd + b1.w);
        *(float4*)(o) = o0;
        *(float4*)(o + 4) = o1;
    } else {
        *(float4*)(o) = make_float4(acc[0], acc[1], acc[2], acc[3]);
        *(float4*)(o + 4) = make_float4(acc[4], acc[5], acc[6], acc[7]);
    }
}

// ---------- dense GEMM: Y = (X * iscale?) @ W (+ bias?), rows scaled by oscale?, fp16/fp32 out ----------
template <int C, bool ISCALE, bool OSCALE, bool BIAS, bool F16OUT>
__global__ __launch_bounds__(512) void gemm_kernel(const float* __restrict__ X,
                                                   const float* __restrict__ W,
                                                   const float* __restrict__ bias,
                                                   const float* __restrict__ iscale,
                                                   const float* __restrict__ oscale,
                                                   void* __restrict__ Yv, int n) {
    constexpr int K = DK;
    constexpr int BM = 128;
    constexpr int KP = K + 4;
    constexpr int COLT = C / 4;
    constexpr int ROWT = 512 / COLT;
    constexpr int RPT = BM / ROWT;

    __shared__ float sW[K][C];
    __shared__ float sX[BM][KP];

    const int tid = threadIdx.x;
    const int row0 = blockIdx.x * BM;

    for (int i = tid; i < K * C / 4; i += 512) {
        float4 w = ((const float4*)W)[i];
        int k = i / (C / 4);
        int cc = i % (C / 4);
        *(float4*)&sW[k][cc * 4] = w;
    }
    for (int i = tid; i < BM * (K / 4); i += 512) {
        int r = i / (K / 4);
        int kc = i % (K / 4);
        int gr = row0 + r;
        float4 v = make_float4(0.f, 0.f, 0.f, 0.f);
        if (gr < n) {
            v = *(const float4*)(X + (size_t)gr * K + kc * 4);
            if (ISCALE) {
                float s = iscale[gr];
                v.x *= s; v.y *= s; v.z *= s; v.w *= s;
            }
        }
        *(float4*)&sX[r][kc * 4] = v;
    }
    __syncthreads();

    const int tc = tid % COLT;
    const int tr = tid / COLT;
    const int c0 = tc * 4;
    const int r0 = tr * RPT;

    float acc[RPT][4];
#pragma unroll
    for (int i = 0; i < RPT; ++i)
#pragma unroll
        for (int j = 0; j < 4; ++j) acc[i][j] = 0.f;

    for (int k = 0; k < K; k += 4) {
        float wv[4][4];
#pragma unroll
        for (int j = 0; j < 4; ++j) {
            float4 t = *(const float4*)&sW[k + j][c0];
            wv[j][0] = t.x; wv[j][1] = t.y; wv[j][2] = t.z; wv[j][3] = t.w;
        }
#pragma unroll
        for (int i = 0; i < RPT; ++i) {
            float4 xv = *(const float4*)&sX[r0 + i][k];
#pragma unroll
            for (int j = 0; j < 4; ++j) {
                acc[i][j] += xv.x * wv[0][j] + xv.y * wv[1][j] +
                             xv.z * wv[2][j] + xv.w * wv[3][j];
            }
        }
    }

    float bv[4] = {0.f, 0.f, 0.f, 0.f};
    if (BIAS) {
        float4 t = ((const float4*)bias)[tc];
        bv[0] = t.x; bv[1] = t.y; bv[2] = t.z; bv[3] = t.w;
    }
#pragma unroll
    for (int i = 0; i < RPT; ++i) {
        int gr = row0 + r0 + i;
        if (gr < n) {
            float os = OSCALE ? oscale[gr] : 1.0f;
            float o0 = (acc[i][0] + bv[0]) * os;
            float o1 = (acc[i][1] + bv[1]) * os;
            float o2 = (acc[i][2] + bv[2]) * os;
            float o3 = (acc[i][3] + bv[3]) * os;
            if constexpr (F16OUT) {
                _Float16* Y = (_Float16*)Yv;
                f16x4 h;
                h[0] = (_Float16)o0; h[1] = (_Float16)o1;
                h[2] = (_Float16)o2; h[3] = (_Float16)o3;
                *(f16x4*)(Y + (size_t)gr * C + c0) = h;
            } else {
                float* Y = (float*)Yv;
                *(float4*)(Y + (size_t)gr * C + c0) = make_float4(o0, o1, o2, o3);
            }
        }
    }
}

static inline int cdiv(long long a, long long b) { return (int)((a + b - 1) / b); }

extern "C" void kernel_launch(void* const* d_in, const int* in_sizes, int n_in,
                              void* d_out, int out_size, void* d_ws, size_t ws_size,
                              hipStream_t stream) {
    const float* feat = (const float*)d_in[0];
    const float* W0   = (const float*)d_in[1];
    const float* b0   = (const float*)d_in[2];
    const float* W1   = (const float*)d_in[3];
    const float* b1   = (const float*)d_in[4];
    const float* W2   = (const float*)d_in[5];
    const float* b2   = (const float*)d_in[6];
    const int*   src  = (const int*)d_in[7];
    const int*   dst  = (const int*)d_in[8];

    const int N = in_sizes[0] / DK;
    const int E = in_sizes[7];

    // ws (floats): nsrc[N] ndst[N] rp[N+1] csum[256] coffs[256] eidx[E]
    //              agg[N*128] h1[N*128]
    // aliases: deg_out/deg_in/cur -> agg region (dead before gather0 writes agg)
    //          feat16 & h0_16 (fp16 N*128) -> h1 region (dead before gemm1 writes h1)
    //          y2_16 (fp16 N*64) -> agg region (agg dead after gemm1 reads it)
    float* ws      = (float*)d_ws;
    float* nsrc    = ws;
    float* ndst    = ws + N;
    int*   rp      = (int*)(ws + 2 * (size_t)N);
    int*   csum    = rp + (N + 1);
    int*   coffs   = csum + 256;
    int*   eidx    = coffs + 256;
    size_t aoff    = (size_t)(3 * (size_t)N + 513 + E + 3) & ~(size_t)3;
    float* agg     = ws + aoff;                       // [N*128] fp32
    float* h1      = agg + (size_t)N * 128;           // [N*128] fp32
    int*   deg_out = (int*)agg;
    int*   deg_in  = deg_out + N;
    int*   cur     = deg_in + N;
    _Float16* x16  = (_Float16*)h1;                   // feat16, then h0_16
    _Float16* y216 = (_Float16*)agg;                  // layer-2 fp16 y2

    const int chunks = cdiv(N, 2048);

    // ---- CSR build + norms ----
    hipMemsetAsync(deg_out, 0, 2 * (size_t)N * sizeof(int), stream);
    deg_kernel<<<cdiv(E, 256), 256, 0, stream>>>(src, dst, deg_out, deg_in, E);
    norm_kernel<<<cdiv(N, 256), 256, 0, stream>>>(deg_out, deg_in, nsrc, ndst, N);
    scanA<<<chunks, 256, 0, stream>>>(deg_in, rp, csum, N);
    scanB<<<1, 256, 0, stream>>>(csum, coffs, chunks);
    scanC<<<chunks, 256, 0, stream>>>(deg_in, coffs, rp, cur, N);
    fill_kernel<<<cdiv(E, 256), 256, 0, stream>>>(src, dst, cur, eidx, E);

    const int gemm_blocks = cdiv(N, 128);
    const int gat128 = cdiv(N, 16);   // TPN=16, 16 nodes/block
    const int gat64  = cdiv(N, 32);   // TPN=8, 32 nodes/block

    // ---- layer 0 ----
    // feat16 = fp16(nsrc*feat)
    cvt_scale_kernel<<<cdiv((long long)N * 16, 256), 256, 0, stream>>>(feat, nsrc, x16, N * 16);
    // agg = A * feat16
    spmm_gather16<128, false><<<gat128, 256, 0, stream>>>(x16, eidx, rp, nullptr, nullptr, agg, N);
    // h0_16 = fp16( nsrc * ((ndst*agg)@W0 + b0) )   [overwrites feat16]
    gemm_kernel<128, true, true, true, true><<<gemm_blocks, 512, 0, stream>>>(
        agg, W0, b0, ndst, nsrc, (void*)x16, N);

    // ---- layer 1 ----
    spmm_gather16<128, false><<<gat128, 256, 0, stream>>>(x16, eidx, rp, nullptr, nullptr, agg, N);
    // h1 = (ndst*agg)@W1 + b1   (fp32; consumed linearly by gemm64)
    gemm_kernel<128, true, false, true, false><<<gemm_blocks, 512, 0, stream>>>(
        agg, W1, b1, ndst, nullptr, (void*)h1, N);

    // ---- layer 2 ----
    // y2_16 = fp16( nsrc*(h1@W2) )   [into agg region]
    gemm_kernel<64, false, true, false, true><<<gemm_blocks, 512, 0, stream>>>(
        h1, W2, nullptr, nullptr, nsrc, (void*)y216, N);
    // out = ndst*(A*y2_16) + b2
    spmm_gather16<64, true><<<gat64, 256, 0, stream>>>(y216, eidx, rp, ndst, b2, (float*)d_out, N);
}

// Round 6
// 588.385 us; speedup vs baseline: 1.5216x; 1.2019x over previous
//
#include <hip/hip_runtime.h>
#include <hip/hip_fp16.h>

// GCN encoder: 3 layers of  out = Ddst^-1/2 * A * Dsrc^-1/2 * X * W + b
// N=100000, E=1600000, dims 128->128->128->64, all fp32 in/out.
//
// Round 5: locality-staged CSR build (round-4 fill_kernel wrote 105 MB for a
// 6.4 MB eidx via random 4B scatter; deg+scan+fill ~190us total).
//  - p1: LDS-binned coarse histogram (dst>>9) + out-degree atomics
//  - p2: scan 256 bin counts
//  - p3: block-level binning: LDS count -> one cursor reservation per
//        (block,bin) -> contiguous-run writes of (src,dst) into binbuf
//  - p4: one block per bin: LDS histogram+scan -> rp & ndst written here,
//        LDS-cursor scatter of src into eidx (hot 32KB region per block)
// Compute pipeline (unchanged from round 4): fp16 gather operands, fp32
// accumulate; norms folded into producer epilogues.

#define DK 128
#define BIN_SHIFT 9
#define BIN_SIZE 512
#define NBINS_MAX 256
#define P3_CHUNK 8192

typedef _Float16 f16x8 __attribute__((ext_vector_type(8)));
typedef _Float16 f16x4 __attribute__((ext_vector_type(4)));

// ---------- p1: coarse bin count (LDS) + out-degree (global atomics) ----------
__global__ __launch_bounds__(256) void p1_count(const int* __restrict__ src,
                                                const int* __restrict__ dst,
                                                int* __restrict__ deg_out,
                                                int* __restrict__ bin_cnt, int E) {
    __shared__ int hist[NBINS_MAX];
    const int tid = threadIdx.x;
    hist[tid] = 0;
    __syncthreads();
    const int stride = gridDim.x * 256;
    for (int e = blockIdx.x * 256 + tid; e < E; e += stride) {
        atomicAdd(&deg_out[src[e]], 1);
        atomicAdd(&hist[dst[e] >> BIN_SHIFT], 1);
    }
    __syncthreads();
    int h = hist[tid];
    if (h) atomicAdd(&bin_cnt[tid], h);
}

// ---------- p2: exclusive scan of 256 bin counts ----------
__global__ __launch_bounds__(256) void p2_scan(const int* __restrict__ bin_cnt,
                                               int* __restrict__ bin_base,
                                               int* __restrict__ bin_cur) {
    __shared__ int wsum[4];
    const int tid = threadIdx.x;
    int v = bin_cnt[tid];
    const int lane = tid & 63, w = tid >> 6;
    int sc = v;
#pragma unroll
    for (int off = 1; off < 64; off <<= 1) {
        int t = __shfl_up(sc, off, 64);
        if (lane >= off) sc += t;
    }
    if (lane == 63) wsum[w] = sc;
    __syncthreads();
    int woff = 0;
    for (int k = 0; k < w; ++k) woff += wsum[k];
    int excl = woff + sc - v;
    bin_base[tid] = excl;
    bin_cur[tid] = excl;
}

// ---------- p3: block-level binning scatter into binbuf ----------
__global__ __launch_bounds__(256) void p3_scatter(const int* __restrict__ src,
                                                  const int* __restrict__ dst,
                                                  int* __restrict__ bin_cur,
                                                  uint2* __restrict__ binbuf, int E) {
    __shared__ int cnt[NBINS_MAX];
    __shared__ int ofs[NBINS_MAX];
    const int tid = threadIdx.x;
    const int c0 = blockIdx.x * P3_CHUNK;
    const int c1 = min(E, c0 + P3_CHUNK);
    cnt[tid] = 0;
    __syncthreads();
    for (int i = c0 + tid; i < c1; i += 256)
        atomicAdd(&cnt[dst[i] >> BIN_SHIFT], 1);
    __syncthreads();
    int c = cnt[tid];
    if (c > 0) ofs[tid] = atomicAdd(&bin_cur[tid], c);
    __syncthreads();
    cnt[tid] = 0;
    __syncthreads();
    for (int i = c0 + tid; i < c1; i += 256) {
        int d = dst[i];
        int b = d >> BIN_SHIFT;
        int p = ofs[b] + atomicAdd(&cnt[b], 1);
        binbuf[p] = make_uint2((unsigned)src[i], (unsigned)d);
    }
}

// ---------- nsrc = rsqrt(max(out_deg,1)) ----------
__global__ __launch_bounds__(256) void nsrc_kernel(const int* __restrict__ deg_out,
                                                   float* __restrict__ nsrc, int n) {
    int i = blockIdx.x * blockDim.x + threadIdx.x;
    if (i < n) nsrc[i] = rsqrtf(fmaxf((float)deg_out[i], 1.0f));
}

// ---------- p4: per-bin finalize: rp, ndst, eidx ----------
__global__ __launch_bounds__(256) void p4_finalize(const uint2* __restrict__ binbuf,
                                                   const int* __restrict__ bin_base,
                                                   const int* __restrict__ bin_cnt,
                                                   int* __restrict__ rp,
                                                   float* __restrict__ ndst,
                                                   int* __restrict__ eidx, int n) {
    __shared__ int hist[BIN_SIZE];
    __shared__ int wsum[4];
    const int tid = threadIdx.x;
    const int b = blockIdx.x;
    const int ebase = bin_base[b];
    const int count = bin_cnt[b];
    hist[tid] = 0;
    hist[tid + 256] = 0;
    __syncthreads();
    const uint2* ebuf = binbuf + ebase;
    for (int i = tid; i < count; i += 256)
        atomicAdd(&hist[ebuf[i].y & (BIN_SIZE - 1)], 1);
    __syncthreads();
    int v0 = hist[2 * tid], v1 = hist[2 * tid + 1];
    int s = v0 + v1;
    const int lane = tid & 63, w = tid >> 6;
    int sc = s;
#pragma unroll
    for (int off = 1; off < 64; off <<= 1) {
        int t = __shfl_up(sc, off, 64);
        if (lane >= off) sc += t;
    }
    if (lane == 63) wsum[w] = sc;
    __syncthreads();
    int woff = 0;
    for (int k = 0; k < w; ++k) woff += wsum[k];
    const int b0 = woff + sc - s;   // exclusive base, local node 2*tid
    const int b1 = b0 + v0;         // local node 2*tid+1
    const int g0 = (b << BIN_SHIFT) + 2 * tid;
    if (g0 < n) { rp[g0] = ebase + b0; ndst[g0] = rsqrtf(fmaxf((float)v0, 1.0f)); }
    if (g0 + 1 < n) { rp[g0 + 1] = ebase + b1; ndst[g0 + 1] = rsqrtf(fmaxf((float)v1, 1.0f)); }
    if (b == gridDim.x - 1 && tid == 0) rp[n] = ebase + count;
    __syncthreads();
    hist[2 * tid] = b0;
    hist[2 * tid + 1] = b1;
    __syncthreads();
    for (int i = tid; i < count; i += 256) {
        uint2 e = ebuf[i];
        int p = ebase + atomicAdd(&hist[e.y & (BIN_SIZE - 1)], 1);
        eidx[p] = (int)e.x;
    }
}

// ---------- convert + row-scale: o[r,:] = fp16(x[r,:] * scale[r]), D=128 ----------
__global__ __launch_bounds__(256) void cvt_scale_kernel(const float* __restrict__ x,
                                                        const float* __restrict__ scale,
                                                        _Float16* __restrict__ o, int n8) {
    int i = blockIdx.x * blockDim.x + threadIdx.x;
    if (i >= n8) return;
    int row = i >> 4;
    float s = scale[row];
    const float4 v0 = *(const float4*)(x + (size_t)i * 8);
    const float4 v1 = *(const float4*)(x + (size_t)i * 8 + 4);
    f16x8 r;
    r[0] = (_Float16)(v0.x * s); r[1] = (_Float16)(v0.y * s);
    r[2] = (_Float16)(v0.z * s); r[3] = (_Float16)(v0.w * s);
    r[4] = (_Float16)(v1.x * s); r[5] = (_Float16)(v1.y * s);
    r[6] = (_Float16)(v1.z * s); r[7] = (_Float16)(v1.w * s);
    *(f16x8*)(o + (size_t)i * 8) = r;
}

// ---------- SpMM gather over fp16 rows ----------
template <int D, bool FINAL>
__global__ __launch_bounds__(256) void spmm_gather16(const _Float16* __restrict__ x,
                                                     const int* __restrict__ eidx,
                                                     const int* __restrict__ rp,
                                                     const float* __restrict__ ndst,
                                                     const float* __restrict__ bias,
                                                     float* __restrict__ out, int n) {
    constexpr int TPN = D / 8;
    constexpr int NPB = 256 / TPN;
    const int node = blockIdx.x * NPB + threadIdx.x / TPN;
    const int lane = threadIdx.x % TPN;
    if (node >= n) return;
    const int beg = rp[node];
    const int end = rp[node + 1];
    float acc[8] = {0.f, 0.f, 0.f, 0.f, 0.f, 0.f, 0.f, 0.f};
#pragma unroll 2
    for (int e = beg; e < end; ++e) {
        int s = eidx[e];
        f16x8 v = *(const f16x8*)(x + (size_t)s * D + lane * 8);
#pragma unroll
        for (int j = 0; j < 8; ++j) acc[j] += (float)v[j];
    }
    float* o = out + (size_t)node * D + lane * 8;
    if (FINAL) {
        float sd = ndst[node];
        float4 c0 = *(const float4*)(bias + lane * 8);
        float4 c1 = *(const float4*)(bias + lane * 8 + 4);
        *(float4*)(o) = make_float4(acc[0] * sd + c0.x, acc[1] * sd + c0.y,
                                    acc[2] * sd + c0.z, acc[3] * sd + c0.w);
        *(float4*)(o + 4) = make_float4(acc[4] * sd + c1.x, acc[5] * sd + c1.y,
                                        acc[6] * sd + c1.z, acc[7] * sd + c1.w);
    } else {
        *(float4*)(o) = make_float4(acc[0], acc[1], acc[2], acc[3]);
        *(float4*)(o + 4) = make_float4(acc[4], acc[5], acc[6], acc[7]);
    }
}

// ---------- dense GEMM: Y = (X * iscale?) @ W (+ bias?), rows scaled by oscale? ----------
template <int C, bool ISCALE, bool OSCALE, bool BIAS, bool F16OUT>
__global__ __launch_bounds__(512) void gemm_kernel(const float* __restrict__ X,
                                                   const float* __restrict__ W,
                                                   const float* __restrict__ bias,
                                                   const float* __restrict__ iscale,
                                                   const float* __restrict__ oscale,
                                                   void* __restrict__ Yv, int n) {
    constexpr int K = DK;
    constexpr int BM = 128;
    constexpr int KP = K + 4;
    constexpr int COLT = C / 4;
    constexpr int ROWT = 512 / COLT;
    constexpr int RPT = BM / ROWT;

    __shared__ float sW[K][C];
    __shared__ float sX[BM][KP];

    const int tid = threadIdx.x;
    const int row0 = blockIdx.x * BM;

    for (int i = tid; i < K * C / 4; i += 512) {
        float4 w = ((const float4*)W)[i];
        int k = i / (C / 4);
        int cc = i % (C / 4);
        *(float4*)&sW[k][cc * 4] = w;
    }
    for (int i = tid; i < BM * (K / 4); i += 512) {
        int r = i / (K / 4);
        int kc = i % (K / 4);
        int gr = row0 + r;
        float4 v = make_float4(0.f, 0.f, 0.f, 0.f);
        if (gr < n) {
            v = *(const float4*)(X + (size_t)gr * K + kc * 4);
            if (ISCALE) {
                float s = iscale[gr];
                v.x *= s; v.y *= s; v.z *= s; v.w *= s;
            }
        }
        *(float4*)&sX[r][kc * 4] = v;
    }
    __syncthreads();

    const int tc = tid % COLT;
    const int tr = tid / COLT;
    const int c0 = tc * 4;
    const int r0 = tr * RPT;

    float acc[RPT][4];
#pragma unroll
    for (int i = 0; i < RPT; ++i)
#pragma unroll
        for (int j = 0; j < 4; ++j) acc[i][j] = 0.f;

    for (int k = 0; k < K; k += 4) {
        float wv[4][4];
#pragma unroll
        for (int j = 0; j < 4; ++j) {
            float4 t = *(const float4*)&sW[k + j][c0];
            wv[j][0] = t.x; wv[j][1] = t.y; wv[j][2] = t.z; wv[j][3] = t.w;
        }
#pragma unroll
        for (int i = 0; i < RPT; ++i) {
            float4 xv = *(const float4*)&sX[r0 + i][k];
#pragma unroll
            for (int j = 0; j < 4; ++j) {
                acc[i][j] += xv.x * wv[0][j] + xv.y * wv[1][j] +
                             xv.z * wv[2][j] + xv.w * wv[3][j];
            }
        }
    }

    float bv[4] = {0.f, 0.f, 0.f, 0.f};
    if (BIAS) {
        float4 t = ((const float4*)bias)[tc];
        bv[0] = t.x; bv[1] = t.y; bv[2] = t.z; bv[3] = t.w;
    }
#pragma unroll
    for (int i = 0; i < RPT; ++i) {
        int gr = row0 + r0 + i;
        if (gr < n) {
            float os = OSCALE ? oscale[gr] : 1.0f;
            float o0 = (acc[i][0] + bv[0]) * os;
            float o1 = (acc[i][1] + bv[1]) * os;
            float o2 = (acc[i][2] + bv[2]) * os;
            float o3 = (acc[i][3] + bv[3]) * os;
            if constexpr (F16OUT) {
                _Float16* Y = (_Float16*)Yv;
                f16x4 h;
                h[0] = (_Float16)o0; h[1] = (_Float16)o1;
                h[2] = (_Float16)o2; h[3] = (_Float16)o3;
                *(f16x4*)(Y + (size_t)gr * C + c0) = h;
            } else {
                float* Y = (float*)Yv;
                *(float4*)(Y + (size_t)gr * C + c0) = make_float4(o0, o1, o2, o3);
            }
        }
    }
}

static inline int cdiv(long long a, long long b) { return (int)((a + b - 1) / b); }

extern "C" void kernel_launch(void* const* d_in, const int* in_sizes, int n_in,
                              void* d_out, int out_size, void* d_ws, size_t ws_size,
                              hipStream_t stream) {
    const float* feat = (const float*)d_in[0];
    const float* W0   = (const float*)d_in[1];
    const float* b0   = (const float*)d_in[2];
    const float* W1   = (const float*)d_in[3];
    const float* b1   = (const float*)d_in[4];
    const float* W2   = (const float*)d_in[5];
    const float* b2   = (const float*)d_in[6];
    const int*   src  = (const int*)d_in[7];
    const int*   dst  = (const int*)d_in[8];

    const int N = in_sizes[0] / DK;
    const int E = in_sizes[7];

    // ws (4B units): nsrc[N] ndst[N] rp[N+1] bin_cnt[256] bin_base[256]
    //                bin_cur[256] eidx[E] | agg[N*128] h1[N*128]
    // aliases: deg_out -> agg start (dead after nsrc_kernel, before gather0)
    //          binbuf (uint2, E) -> h1 start (dead before cvt_scale writes x16)
    //          x16/h0_16 (fp16 N*128) -> h1 region; y2_16 (fp16 N*64) -> agg
    float* ws       = (float*)d_ws;
    float* nsrc     = ws;
    float* ndst     = ws + N;
    int*   rp       = (int*)(ws + 2 * (size_t)N);
    int*   bin_cnt  = rp + (N + 1);
    int*   bin_base = bin_cnt + NBINS_MAX;
    int*   bin_cur  = bin_base + NBINS_MAX;
    int*   eidx     = bin_cur + NBINS_MAX;
    size_t aoff     = (size_t)(3 * (size_t)N + 1 + 3 * NBINS_MAX + E + 3) & ~(size_t)3;
    float* agg      = ws + aoff;                       // [N*128] fp32
    float* h1       = agg + (size_t)N * 128;           // [N*128] fp32
    int*   deg_out  = (int*)agg;
    uint2* binbuf   = (uint2*)h1;
    _Float16* x16   = (_Float16*)h1;
    _Float16* y216  = (_Float16*)agg;

    const int NBINS_USED = cdiv(N, BIN_SIZE);

    // ---- CSR build + norms ----
    hipMemsetAsync(deg_out, 0, (size_t)N * sizeof(int), stream);
    hipMemsetAsync(bin_cnt, 0, NBINS_MAX * sizeof(int), stream);
    p1_count<<<1024, 256, 0, stream>>>(src, dst, deg_out, bin_cnt, E);
    p2_scan<<<1, 256, 0, stream>>>(bin_cnt, bin_base, bin_cur);
    p3_scatter<<<cdiv(E, P3_CHUNK), 256, 0, stream>>>(src, dst, bin_cur, binbuf, E);
    nsrc_kernel<<<cdiv(N, 256), 256, 0, stream>>>(deg_out, nsrc, N);
    p4_finalize<<<NBINS_USED, 256, 0, stream>>>(binbuf, bin_base, bin_cnt, rp, ndst, eidx, N);

    const int gemm_blocks = cdiv(N, 128);
    const int gat128 = cdiv(N, 16);   // TPN=16, 16 nodes/block
    const int gat64  = cdiv(N, 32);   // TPN=8, 32 nodes/block

    // ---- layer 0 ----
    cvt_scale_kernel<<<cdiv((long long)N * 16, 256), 256, 0, stream>>>(feat, nsrc, x16, N * 16);
    spmm_gather16<128, false><<<gat128, 256, 0, stream>>>(x16, eidx, rp, nullptr, nullptr, agg, N);
    gemm_kernel<128, true, true, true, true><<<gemm_blocks, 512, 0, stream>>>(
        agg, W0, b0, ndst, nsrc, (void*)x16, N);

    // ---- layer 1 ----
    spmm_gather16<128, false><<<gat128, 256, 0, stream>>>(x16, eidx, rp, nullptr, nullptr, agg, N);
    gemm_kernel<128, true, false, true, false><<<gemm_blocks, 512, 0, stream>>>(
        agg, W1, b1, ndst, nullptr, (void*)h1, N);

    // ---- layer 2 ----
    gemm_kernel<64, false, true, false, true><<<gemm_blocks, 512, 0, stream>>>(
        h1, W2, nullptr, nullptr, nsrc, (void*)y216, N);
    spmm_gather16<64, true><<<gat64, 256, 0, stream>>>(y216, eidx, rp, ndst, b2, (float*)d_out, N);
}

// Round 7
// 476.483 us; speedup vs baseline: 1.8790x; 1.2349x over previous
//
#include <hip/hip_runtime.h>
#include <hip/hip_fp16.h>

// GCN encoder: 3 layers of  out = Ddst^-1/2 * A * Dsrc^-1/2 * X * W + b
// N=100000, E=1600000, dims 128->128->128->64, all fp32 in/out.
//
// Round 6: MFMA (16x16x32 f16) GEMMs + all-fp16 intermediates.
//  - CSR build: locality-staged binning (round 5, unchanged)
//  - gathers (layers 0/1): fp16 in, fp32 accum, fold ndst, fp16 out
//  - GEMMs: no-LDS MFMA kernels; A = fp16 rows (16B frag loads), B = fp16
//    W pre-transposed to [C][K] (L1-resident); fp32 accumulate + epilogue
//  - chain: x16=nsrc*feat -> agg0=ndst*A*x16 -> h0=nsrc*(agg0@W0+b0)
//           -> agg1=ndst*A*h0 -> h1=agg1@W1+b1 -> y2=nsrc*(h1@W2)
//           -> out = ndst*(A*y2) + b2  (fp32)
// Requires N % 16 == 0 (N=100000 ok).

#define DK 128
#define BIN_SHIFT 9
#define BIN_SIZE 512
#define NBINS_MAX 256
#define P3_CHUNK 8192

typedef _Float16 f16x8 __attribute__((ext_vector_type(8)));
typedef float f32x4 __attribute__((ext_vector_type(4)));

// ---------- p1: coarse bin count (LDS) + out-degree (global atomics) ----------
__global__ __launch_bounds__(256) void p1_count(const int* __restrict__ src,
                                                const int* __restrict__ dst,
                                                int* __restrict__ deg_out,
                                                int* __restrict__ bin_cnt, int E) {
    __shared__ int hist[NBINS_MAX];
    const int tid = threadIdx.x;
    hist[tid] = 0;
    __syncthreads();
    const int stride = gridDim.x * 256;
    for (int e = blockIdx.x * 256 + tid; e < E; e += stride) {
        atomicAdd(&deg_out[src[e]], 1);
        atomicAdd(&hist[dst[e] >> BIN_SHIFT], 1);
    }
    __syncthreads();
    int h = hist[tid];
    if (h) atomicAdd(&bin_cnt[tid], h);
}

// ---------- p2: exclusive scan of 256 bin counts ----------
__global__ __launch_bounds__(256) void p2_scan(const int* __restrict__ bin_cnt,
                                               int* __restrict__ bin_base,
                                               int* __restrict__ bin_cur) {
    __shared__ int wsum[4];
    const int tid = threadIdx.x;
    int v = bin_cnt[tid];
    const int lane = tid & 63, w = tid >> 6;
    int sc = v;
#pragma unroll
    for (int off = 1; off < 64; off <<= 1) {
        int t = __shfl_up(sc, off, 64);
        if (lane >= off) sc += t;
    }
    if (lane == 63) wsum[w] = sc;
    __syncthreads();
    int woff = 0;
    for (int k = 0; k < w; ++k) woff += wsum[k];
    int excl = woff + sc - v;
    bin_base[tid] = excl;
    bin_cur[tid] = excl;
}

// ---------- p3: block-level binning scatter into binbuf ----------
__global__ __launch_bounds__(256) void p3_scatter(const int* __restrict__ src,
                                                  const int* __restrict__ dst,
                                                  int* __restrict__ bin_cur,
                                                  uint2* __restrict__ binbuf, int E) {
    __shared__ int cnt[NBINS_MAX];
    __shared__ int ofs[NBINS_MAX];
    const int tid = threadIdx.x;
    const int c0 = blockIdx.x * P3_CHUNK;
    const int c1 = min(E, c0 + P3_CHUNK);
    cnt[tid] = 0;
    __syncthreads();
    for (int i = c0 + tid; i < c1; i += 256)
        atomicAdd(&cnt[dst[i] >> BIN_SHIFT], 1);
    __syncthreads();
    int c = cnt[tid];
    if (c > 0) ofs[tid] = atomicAdd(&bin_cur[tid], c);
    __syncthreads();
    cnt[tid] = 0;
    __syncthreads();
    for (int i = c0 + tid; i < c1; i += 256) {
        int d = dst[i];
        int b = d >> BIN_SHIFT;
        int p = ofs[b] + atomicAdd(&cnt[b], 1);
        binbuf[p] = make_uint2((unsigned)src[i], (unsigned)d);
    }
}

// ---------- nsrc = rsqrt(max(out_deg,1)) ----------
__global__ __launch_bounds__(256) void nsrc_kernel(const int* __restrict__ deg_out,
                                                   float* __restrict__ nsrc, int n) {
    int i = blockIdx.x * blockDim.x + threadIdx.x;
    if (i < n) nsrc[i] = rsqrtf(fmaxf((float)deg_out[i], 1.0f));
}

// ---------- p4: per-bin finalize: rp, ndst, eidx ----------
__global__ __launch_bounds__(256) void p4_finalize(const uint2* __restrict__ binbuf,
                                                   const int* __restrict__ bin_base,
                                                   const int* __restrict__ bin_cnt,
                                                   int* __restrict__ rp,
                                                   float* __restrict__ ndst,
                                                   int* __restrict__ eidx, int n) {
    __shared__ int hist[BIN_SIZE];
    __shared__ int wsum[4];
    const int tid = threadIdx.x;
    const int b = blockIdx.x;
    const int ebase = bin_base[b];
    const int count = bin_cnt[b];
    hist[tid] = 0;
    hist[tid + 256] = 0;
    __syncthreads();
    const uint2* ebuf = binbuf + ebase;
    for (int i = tid; i < count; i += 256)
        atomicAdd(&hist[ebuf[i].y & (BIN_SIZE - 1)], 1);
    __syncthreads();
    int v0 = hist[2 * tid], v1 = hist[2 * tid + 1];
    int s = v0 + v1;
    const int lane = tid & 63, w = tid >> 6;
    int sc = s;
#pragma unroll
    for (int off = 1; off < 64; off <<= 1) {
        int t = __shfl_up(sc, off, 64);
        if (lane >= off) sc += t;
    }
    if (lane == 63) wsum[w] = sc;
    __syncthreads();
    int woff = 0;
    for (int k = 0; k < w; ++k) woff += wsum[k];
    const int b0 = woff + sc - s;
    const int b1 = b0 + v0;
    const int g0 = (b << BIN_SHIFT) + 2 * tid;
    if (g0 < n) { rp[g0] = ebase + b0; ndst[g0] = rsqrtf(fmaxf((float)v0, 1.0f)); }
    if (g0 + 1 < n) { rp[g0 + 1] = ebase + b1; ndst[g0 + 1] = rsqrtf(fmaxf((float)v1, 1.0f)); }
    if (b == gridDim.x - 1 && tid == 0) rp[n] = ebase + count;
    __syncthreads();
    hist[2 * tid] = b0;
    hist[2 * tid + 1] = b1;
    __syncthreads();
    for (int i = tid; i < count; i += 256) {
        uint2 e = ebuf[i];
        int p = ebase + atomicAdd(&hist[e.y & (BIN_SIZE - 1)], 1);
        eidx[p] = (int)e.x;
    }
}

// ---------- convert + row-scale: o[r,:] = fp16(x[r,:] * scale[r]), D=128 ----------
__global__ __launch_bounds__(256) void cvt_scale_kernel(const float* __restrict__ x,
                                                        const float* __restrict__ scale,
                                                        _Float16* __restrict__ o, int n8) {
    int i = blockIdx.x * blockDim.x + threadIdx.x;
    if (i >= n8) return;
    int row = i >> 4;
    float s = scale[row];
    const float4 v0 = *(const float4*)(x + (size_t)i * 8);
    const float4 v1 = *(const float4*)(x + (size_t)i * 8 + 4);
    f16x8 r;
    r[0] = (_Float16)(v0.x * s); r[1] = (_Float16)(v0.y * s);
    r[2] = (_Float16)(v0.z * s); r[3] = (_Float16)(v0.w * s);
    r[4] = (_Float16)(v1.x * s); r[5] = (_Float16)(v1.y * s);
    r[6] = (_Float16)(v1.z * s); r[7] = (_Float16)(v1.w * s);
    *(f16x8*)(o + (size_t)i * 8) = r;
}

// ---------- weight convert+transpose: Wt[c][k] = fp16(W[k][c]) ----------
__global__ __launch_bounds__(256) void wcvt_kernel(const float* __restrict__ W,
                                                   _Float16* __restrict__ Wt,
                                                   int K, int C) {
    int i = blockIdx.x * blockDim.x + threadIdx.x;
    if (i >= K * C) return;
    int k = i / C, c = i % C;
    Wt[(size_t)c * K + k] = (_Float16)W[i];
}

// ---------- SpMM gather over fp16 rows, ndst folded ----------
// !FINAL: out16[r,:] = fp16( ndst[r] * sum_{e in in(r)} x16[src_e,:] )
//  FINAL: out32[r,:] = ndst[r] * sum + bias
template <int D, bool FINAL>
__global__ __launch_bounds__(256) void spmm_gather16(const _Float16* __restrict__ x,
                                                     const int* __restrict__ eidx,
                                                     const int* __restrict__ rp,
                                                     const float* __restrict__ ndst,
                                                     const float* __restrict__ bias,
                                                     void* __restrict__ outv, int n) {
    constexpr int TPN = D / 8;
    constexpr int NPB = 256 / TPN;
    const int node = blockIdx.x * NPB + threadIdx.x / TPN;
    const int lane = threadIdx.x % TPN;
    if (node >= n) return;
    const int beg = rp[node];
    const int end = rp[node + 1];
    float acc[8] = {0.f, 0.f, 0.f, 0.f, 0.f, 0.f, 0.f, 0.f};
#pragma unroll 2
    for (int e = beg; e < end; ++e) {
        int s = eidx[e];
        f16x8 v = *(const f16x8*)(x + (size_t)s * D + lane * 8);
#pragma unroll
        for (int j = 0; j < 8; ++j) acc[j] += (float)v[j];
    }
    const float sd = ndst[node];
    if (FINAL) {
        float* o = (float*)outv + (size_t)node * D + lane * 8;
        float4 c0 = *(const float4*)(bias + lane * 8);
        float4 c1 = *(const float4*)(bias + lane * 8 + 4);
        *(float4*)(o) = make_float4(acc[0] * sd + c0.x, acc[1] * sd + c0.y,
                                    acc[2] * sd + c0.z, acc[3] * sd + c0.w);
        *(float4*)(o + 4) = make_float4(acc[4] * sd + c1.x, acc[5] * sd + c1.y,
                                        acc[6] * sd + c1.z, acc[7] * sd + c1.w);
    } else {
        f16x8 r;
#pragma unroll
        for (int j = 0; j < 8; ++j) r[j] = (_Float16)(acc[j] * sd);
        *(f16x8*)((_Float16*)outv + (size_t)node * D + lane * 8) = r;
    }
}

// ---------- MFMA GEMM: Y16[n][C] = fp16( oscale? * (A16[n][128] @ W + bias?) ) ----------
// A row-major fp16; Wt = W^T, [C][128] fp16. One wave = 16 rows x C cols.
// Requires n % 16 == 0.
template <int C, bool OSCALE, bool BIAS>
__global__ __launch_bounds__(256) void mfma_gemm(const _Float16* __restrict__ A,
                                                 const _Float16* __restrict__ Wt,
                                                 const float* __restrict__ bias,
                                                 const float* __restrict__ oscale,
                                                 _Float16* __restrict__ Y, int n) {
    constexpr int K = DK;   // 128
    const int wid = threadIdx.x >> 6;
    const int lane = threadIdx.x & 63;
    const int row0 = (blockIdx.x * 4 + wid) * 16;
    if (row0 >= n) return;
    const int lr = lane & 15;          // A row / B col within tile
    const int lk = (lane >> 4) * 8;    // k-offset within 32-chunk

    // A fragments: a[s] covers k in [s*32, s*32+32)
    f16x8 a[4];
    const _Float16* arow = A + (size_t)(row0 + lr) * K + lk;
#pragma unroll
    for (int s = 0; s < 4; ++s) a[s] = *(const f16x8*)(arow + s * 32);

    const int rbase = row0 + (lane >> 4) * 4;
    float os[4];
    if (OSCALE) {
#pragma unroll
        for (int j = 0; j < 4; ++j) os[j] = oscale[rbase + j];
    }

#pragma unroll
    for (int ct = 0; ct < C / 16; ++ct) {
        const int col = ct * 16 + lr;
        const _Float16* wrow = Wt + (size_t)col * K + lk;
        f32x4 acc = {0.f, 0.f, 0.f, 0.f};
#pragma unroll
        for (int s = 0; s < 4; ++s) {
            f16x8 b = *(const f16x8*)(wrow + s * 32);
            acc = __builtin_amdgcn_mfma_f32_16x16x32_f16(a[s], b, acc, 0, 0, 0);
        }
        const float bv = BIAS ? bias[col] : 0.f;
#pragma unroll
        for (int j = 0; j < 4; ++j) {
            float o = acc[j] + bv;
            if (OSCALE) o *= os[j];
            Y[(size_t)(rbase + j) * C + col] = (_Float16)o;
        }
    }
}

static inline int cdiv(long long a, long long b) { return (int)((a + b - 1) / b); }

extern "C" void kernel_launch(void* const* d_in, const int* in_sizes, int n_in,
                              void* d_out, int out_size, void* d_ws, size_t ws_size,
                              hipStream_t stream) {
    const float* feat = (const float*)d_in[0];
    const float* W0   = (const float*)d_in[1];
    const float* b0   = (const float*)d_in[2];
    const float* W1   = (const float*)d_in[3];
    const float* b1   = (const float*)d_in[4];
    const float* W2   = (const float*)d_in[5];
    const float* b2   = (const float*)d_in[6];
    const int*   src  = (const int*)d_in[7];
    const int*   dst  = (const int*)d_in[8];

    const int N = in_sizes[0] / DK;
    const int E = in_sizes[7];

    // ws (4B units): nsrc[N] ndst[N] rp[N+1] bin_cnt/base/cur[3*256] eidx[E]
    //                xbuf[N*64] (fp16 N*128)  abuf[N*64] (fp16 N*128)
    //                Wt0[8192] Wt1[8192] Wt2[4096]  (fp16)
    // aliases: deg_out -> abuf (dead after nsrc_kernel, before gather0 writes)
    //          binbuf (uint2 E = 12.8MB) -> xbuf (dead before cvt_scale)
    // buffer life: xbuf: feat16 -> h0_16 -> h1_16 ; abuf: agg0 -> agg1 -> y2_16
    float* ws       = (float*)d_ws;
    float* nsrc     = ws;
    float* ndst     = ws + N;
    int*   rp       = (int*)(ws + 2 * (size_t)N);
    int*   bin_cnt  = rp + (N + 1);
    int*   bin_base = bin_cnt + NBINS_MAX;
    int*   bin_cur  = bin_base + NBINS_MAX;
    int*   eidx     = bin_cur + NBINS_MAX;
    size_t aoff     = (size_t)(3 * (size_t)N + 1 + 3 * NBINS_MAX + E + 3) & ~(size_t)3;
    _Float16* xbuf  = (_Float16*)(ws + aoff);               // N*128 fp16
    _Float16* abuf  = (_Float16*)(ws + aoff + (size_t)N * 64);
    _Float16* Wt0   = (_Float16*)(ws + aoff + (size_t)N * 128);
    _Float16* Wt1   = Wt0 + 128 * 128;
    _Float16* Wt2   = Wt1 + 128 * 128;
    int*   deg_out  = (int*)abuf;
    uint2* binbuf   = (uint2*)xbuf;

    const int NBINS_USED = cdiv(N, BIN_SIZE);

    // ---- CSR build + norms ----
    hipMemsetAsync(deg_out, 0, (size_t)N * sizeof(int), stream);
    hipMemsetAsync(bin_cnt, 0, NBINS_MAX * sizeof(int), stream);
    p1_count<<<1024, 256, 0, stream>>>(src, dst, deg_out, bin_cnt, E);
    p2_scan<<<1, 256, 0, stream>>>(bin_cnt, bin_base, bin_cur);
    p3_scatter<<<cdiv(E, P3_CHUNK), 256, 0, stream>>>(src, dst, bin_cur, binbuf, E);
    nsrc_kernel<<<cdiv(N, 256), 256, 0, stream>>>(deg_out, nsrc, N);
    p4_finalize<<<NBINS_USED, 256, 0, stream>>>(binbuf, bin_base, bin_cnt, rp, ndst, eidx, N);

    // ---- weight convert+transpose (fp16) ----
    wcvt_kernel<<<cdiv(128 * 128, 256), 256, 0, stream>>>(W0, Wt0, 128, 128);
    wcvt_kernel<<<cdiv(128 * 128, 256), 256, 0, stream>>>(W1, Wt1, 128, 128);
    wcvt_kernel<<<cdiv(128 * 64, 256), 256, 0, stream>>>(W2, Wt2, 128, 64);

    const int gat128 = cdiv(N, 16);   // TPN=16, 16 nodes/block
    const int gat64  = cdiv(N, 32);   // TPN=8, 32 nodes/block
    const int gemm_blocks = cdiv(N, 64);

    // ---- layer 0 ----
    cvt_scale_kernel<<<cdiv((long long)N * 16, 256), 256, 0, stream>>>(feat, nsrc, xbuf, N * 16);
    spmm_gather16<128, false><<<gat128, 256, 0, stream>>>(xbuf, eidx, rp, ndst, nullptr, abuf, N);
    mfma_gemm<128, true, true><<<gemm_blocks, 256, 0, stream>>>(abuf, Wt0, b0, nsrc, xbuf, N);

    // ---- layer 1 ----
    spmm_gather16<128, false><<<gat128, 256, 0, stream>>>(xbuf, eidx, rp, ndst, nullptr, abuf, N);
    mfma_gemm<128, false, true><<<gemm_blocks, 256, 0, stream>>>(abuf, Wt1, b1, nullptr, xbuf, N);

    // ---- layer 2 ----
    mfma_gemm<64, true, false><<<gemm_blocks, 256, 0, stream>>>(xbuf, Wt2, nullptr, nsrc, abuf, N);
    spmm_gather16<64, true><<<gat64, 256, 0, stream>>>(abuf, eidx, rp, ndst, b2, d_out, N);
}

// Round 8
// 417.370 us; speedup vs baseline: 2.1451x; 1.1416x over previous
//
#include <hip/hip_runtime.h>
#include <hip/hip_fp16.h>

// GCN encoder: 3 layers of  out = Ddst^-1/2 * A * Dsrc^-1/2 * X * W + b
// N=100000, E=1600000, dims 128->128->128->64, all fp32 in/out.
//
// Round 7: fully atomic-free-on-global CSR+degree build via dual binning.
//  - p1: LDS histograms of dst>>9 AND src>>9 (no per-node global atomics)
//  - p2: scan both 256-bin segments
//  - p3: dual scatter: (src,dst) pairs by dst-bin -> binbuf; src by src-bin -> srcbuf
//  - p4: per dst-bin: rp, ndst, eidx (LDS hist+scan+cursor scatter)
//  - p4b: per src-bin: LDS histogram -> nsrc (replaces deg atomics + nsrc_kernel)
// Compute pipeline (round 6): fp16 intermediates, fp32-accum gathers with ndst
// folded, no-LDS MFMA 16x16x32 f16 GEMMs with W^T fp16 (L1-resident).

#define DK 128
#define BIN_SHIFT 9
#define BIN_SIZE 512
#define NBINS_MAX 256
#define P3_CHUNK 8192

typedef _Float16 f16x8 __attribute__((ext_vector_type(8)));
typedef float f32x4 __attribute__((ext_vector_type(4)));

// ---------- p1: coarse bin counts for dst and src (LDS only) ----------
__global__ __launch_bounds__(256) void p1_count(const int* __restrict__ src,
                                                const int* __restrict__ dst,
                                                int* __restrict__ bin_cnt, int E) {
    __shared__ int hd[NBINS_MAX];
    __shared__ int hs[NBINS_MAX];
    const int tid = threadIdx.x;
    hd[tid] = 0;
    hs[tid] = 0;
    __syncthreads();
    const int stride = gridDim.x * 256;
    for (int e = blockIdx.x * 256 + tid; e < E; e += stride) {
        atomicAdd(&hd[dst[e] >> BIN_SHIFT], 1);
        atomicAdd(&hs[src[e] >> BIN_SHIFT], 1);
    }
    __syncthreads();
    int d = hd[tid], s = hs[tid];
    if (d) atomicAdd(&bin_cnt[tid], d);
    if (s) atomicAdd(&bin_cnt[NBINS_MAX + tid], s);
}

// ---------- p2: exclusive scan of two independent 256-bin segments ----------
__global__ __launch_bounds__(256) void p2_scan(const int* __restrict__ bin_cnt,
                                               int* __restrict__ bin_base,
                                               int* __restrict__ bin_cur) {
    __shared__ int wsum[4];
    const int tid = threadIdx.x;
    const int lane = tid & 63, w = tid >> 6;
    for (int seg = 0; seg < 2; ++seg) {
        int v = bin_cnt[seg * NBINS_MAX + tid];
        int sc = v;
#pragma unroll
        for (int off = 1; off < 64; off <<= 1) {
            int t = __shfl_up(sc, off, 64);
            if (lane >= off) sc += t;
        }
        if (lane == 63) wsum[w] = sc;
        __syncthreads();
        int woff = 0;
        for (int k = 0; k < w; ++k) woff += wsum[k];
        int excl = woff + sc - v;
        bin_base[seg * NBINS_MAX + tid] = excl;
        bin_cur[seg * NBINS_MAX + tid] = excl;
        __syncthreads();   // protect wsum reuse
    }
}

// ---------- p3: dual binning scatter ----------
__global__ __launch_bounds__(256) void p3_scatter(const int* __restrict__ src,
                                                  const int* __restrict__ dst,
                                                  int* __restrict__ bin_cur,
                                                  uint2* __restrict__ binbuf,
                                                  int* __restrict__ srcbuf, int E) {
    __shared__ int cd[NBINS_MAX];
    __shared__ int cs[NBINS_MAX];
    __shared__ int od[NBINS_MAX];
    __shared__ int osf[NBINS_MAX];
    const int tid = threadIdx.x;
    const int c0 = blockIdx.x * P3_CHUNK;
    const int c1 = min(E, c0 + P3_CHUNK);
    cd[tid] = 0;
    cs[tid] = 0;
    __syncthreads();
    for (int i = c0 + tid; i < c1; i += 256) {
        atomicAdd(&cd[dst[i] >> BIN_SHIFT], 1);
        atomicAdd(&cs[src[i] >> BIN_SHIFT], 1);
    }
    __syncthreads();
    int d = cd[tid], s = cs[tid];
    if (d) od[tid] = atomicAdd(&bin_cur[tid], d);
    if (s) osf[tid] = atomicAdd(&bin_cur[NBINS_MAX + tid], s);
    __syncthreads();
    cd[tid] = 0;
    cs[tid] = 0;
    __syncthreads();
    for (int i = c0 + tid; i < c1; i += 256) {
        int sv = src[i], dv = dst[i];
        int bd = dv >> BIN_SHIFT;
        int p = od[bd] + atomicAdd(&cd[bd], 1);
        binbuf[p] = make_uint2((unsigned)sv, (unsigned)dv);
        int bs = sv >> BIN_SHIFT;
        int q = osf[bs] + atomicAdd(&cs[bs], 1);
        srcbuf[q] = sv;
    }
}

// ---------- p4: per dst-bin finalize: rp, ndst, eidx ----------
__global__ __launch_bounds__(256) void p4_finalize(const uint2* __restrict__ binbuf,
                                                   const int* __restrict__ bin_base,
                                                   const int* __restrict__ bin_cnt,
                                                   int* __restrict__ rp,
                                                   float* __restrict__ ndst,
                                                   int* __restrict__ eidx, int n) {
    __shared__ int hist[BIN_SIZE];
    __shared__ int wsum[4];
    const int tid = threadIdx.x;
    const int b = blockIdx.x;
    const int ebase = bin_base[b];
    const int count = bin_cnt[b];
    hist[tid] = 0;
    hist[tid + 256] = 0;
    __syncthreads();
    const uint2* ebuf = binbuf + ebase;
    for (int i = tid; i < count; i += 256)
        atomicAdd(&hist[ebuf[i].y & (BIN_SIZE - 1)], 1);
    __syncthreads();
    int v0 = hist[2 * tid], v1 = hist[2 * tid + 1];
    int s = v0 + v1;
    const int lane = tid & 63, w = tid >> 6;
    int sc = s;
#pragma unroll
    for (int off = 1; off < 64; off <<= 1) {
        int t = __shfl_up(sc, off, 64);
        if (lane >= off) sc += t;
    }
    if (lane == 63) wsum[w] = sc;
    __syncthreads();
    int woff = 0;
    for (int k = 0; k < w; ++k) woff += wsum[k];
    const int b0 = woff + sc - s;
    const int b1 = b0 + v0;
    const int g0 = (b << BIN_SHIFT) + 2 * tid;
    if (g0 < n) { rp[g0] = ebase + b0; ndst[g0] = rsqrtf(fmaxf((float)v0, 1.0f)); }
    if (g0 + 1 < n) { rp[g0 + 1] = ebase + b1; ndst[g0 + 1] = rsqrtf(fmaxf((float)v1, 1.0f)); }
    if (b == gridDim.x - 1 && tid == 0) rp[n] = ebase + count;
    __syncthreads();
    hist[2 * tid] = b0;
    hist[2 * tid + 1] = b1;
    __syncthreads();
    for (int i = tid; i < count; i += 256) {
        uint2 e = ebuf[i];
        int p = ebase + atomicAdd(&hist[e.y & (BIN_SIZE - 1)], 1);
        eidx[p] = (int)e.x;
    }
}

// ---------- p4b: per src-bin histogram -> nsrc ----------
__global__ __launch_bounds__(256) void p4b_nsrc(const int* __restrict__ srcbuf,
                                                const int* __restrict__ bin_base,
                                                const int* __restrict__ bin_cnt,
                                                float* __restrict__ nsrc, int n) {
    __shared__ int hist[BIN_SIZE];
    const int tid = threadIdx.x;
    const int b = blockIdx.x;
    const int ebase = bin_base[NBINS_MAX + b];
    const int count = bin_cnt[NBINS_MAX + b];
    hist[tid] = 0;
    hist[tid + 256] = 0;
    __syncthreads();
    const int* ebuf = srcbuf + ebase;
    for (int i = tid; i < count; i += 256)
        atomicAdd(&hist[ebuf[i] & (BIN_SIZE - 1)], 1);
    __syncthreads();
    int g = (b << BIN_SHIFT) + tid;
    if (g < n) nsrc[g] = rsqrtf(fmaxf((float)hist[tid], 1.0f));
    g += 256;
    if (g < n) nsrc[g] = rsqrtf(fmaxf((float)hist[tid + 256], 1.0f));
}

// ---------- convert + row-scale: o[r,:] = fp16(x[r,:] * scale[r]), D=128 ----------
__global__ __launch_bounds__(256) void cvt_scale_kernel(const float* __restrict__ x,
                                                        const float* __restrict__ scale,
                                                        _Float16* __restrict__ o, int n8) {
    int i = blockIdx.x * blockDim.x + threadIdx.x;
    if (i >= n8) return;
    int row = i >> 4;
    float s = scale[row];
    const float4 v0 = *(const float4*)(x + (size_t)i * 8);
    const float4 v1 = *(const float4*)(x + (size_t)i * 8 + 4);
    f16x8 r;
    r[0] = (_Float16)(v0.x * s); r[1] = (_Float16)(v0.y * s);
    r[2] = (_Float16)(v0.z * s); r[3] = (_Float16)(v0.w * s);
    r[4] = (_Float16)(v1.x * s); r[5] = (_Float16)(v1.y * s);
    r[6] = (_Float16)(v1.z * s); r[7] = (_Float16)(v1.w * s);
    *(f16x8*)(o + (size_t)i * 8) = r;
}

// ---------- weight convert+transpose (all three in one launch) ----------
__global__ __launch_bounds__(256) void wcvt_all(const float* __restrict__ W0,
                                                const float* __restrict__ W1,
                                                const float* __restrict__ W2,
                                                _Float16* __restrict__ Wt0,
                                                _Float16* __restrict__ Wt1,
                                                _Float16* __restrict__ Wt2) {
    int i = blockIdx.x * 256 + threadIdx.x;
    if (i < 16384) {
        int k = i >> 7, c = i & 127;
        Wt0[(size_t)c * 128 + k] = (_Float16)W0[i];
    } else if (i < 32768) {
        int j = i - 16384;
        int k = j >> 7, c = j & 127;
        Wt1[(size_t)c * 128 + k] = (_Float16)W1[j];
    } else if (i < 40960) {
        int j = i - 32768;
        int k = j >> 6, c = j & 63;
        Wt2[(size_t)c * 128 + k] = (_Float16)W2[j];
    }
}

// ---------- SpMM gather over fp16 rows, ndst folded ----------
template <int D, bool FINAL>
__global__ __launch_bounds__(256) void spmm_gather16(const _Float16* __restrict__ x,
                                                     const int* __restrict__ eidx,
                                                     const int* __restrict__ rp,
                                                     const float* __restrict__ ndst,
                                                     const float* __restrict__ bias,
                                                     void* __restrict__ outv, int n) {
    constexpr int TPN = D / 8;
    constexpr int NPB = 256 / TPN;
    const int node = blockIdx.x * NPB + threadIdx.x / TPN;
    const int lane = threadIdx.x % TPN;
    if (node >= n) return;
    const int beg = rp[node];
    const int end = rp[node + 1];
    float acc[8] = {0.f, 0.f, 0.f, 0.f, 0.f, 0.f, 0.f, 0.f};
#pragma unroll 2
    for (int e = beg; e < end; ++e) {
        int s = eidx[e];
        f16x8 v = *(const f16x8*)(x + (size_t)s * D + lane * 8);
#pragma unroll
        for (int j = 0; j < 8; ++j) acc[j] += (float)v[j];
    }
    const float sd = ndst[node];
    if (FINAL) {
        float* o = (float*)outv + (size_t)node * D + lane * 8;
        float4 c0 = *(const float4*)(bias + lane * 8);
        float4 c1 = *(const float4*)(bias + lane * 8 + 4);
        *(float4*)(o) = make_float4(acc[0] * sd + c0.x, acc[1] * sd + c0.y,
                                    acc[2] * sd + c0.z, acc[3] * sd + c0.w);
        *(float4*)(o + 4) = make_float4(acc[4] * sd + c1.x, acc[5] * sd + c1.y,
                                        acc[6] * sd + c1.z, acc[7] * sd + c1.w);
    } else {
        f16x8 r;
#pragma unroll
        for (int j = 0; j < 8; ++j) r[j] = (_Float16)(acc[j] * sd);
        *(f16x8*)((_Float16*)outv + (size_t)node * D + lane * 8) = r;
    }
}

// ---------- MFMA GEMM: Y16[n][C] = fp16( oscale? * (A16[n][128] @ W + bias?) ) ----------
template <int C, bool OSCALE, bool BIAS>
__global__ __launch_bounds__(256) void mfma_gemm(const _Float16* __restrict__ A,
                                                 const _Float16* __restrict__ Wt,
                                                 const float* __restrict__ bias,
                                                 const float* __restrict__ oscale,
                                                 _Float16* __restrict__ Y, int n) {
    constexpr int K = DK;   // 128
    const int wid = threadIdx.x >> 6;
    const int lane = threadIdx.x & 63;
    const int row0 = (blockIdx.x * 4 + wid) * 16;
    if (row0 >= n) return;
    const int lr = lane & 15;
    const int lk = (lane >> 4) * 8;

    f16x8 a[4];
    const _Float16* arow = A + (size_t)(row0 + lr) * K + lk;
#pragma unroll
    for (int s = 0; s < 4; ++s) a[s] = *(const f16x8*)(arow + s * 32);

    const int rbase = row0 + (lane >> 4) * 4;
    float os[4];
    if (OSCALE) {
#pragma unroll
        for (int j = 0; j < 4; ++j) os[j] = oscale[rbase + j];
    }

#pragma unroll
    for (int ct = 0; ct < C / 16; ++ct) {
        const int col = ct * 16 + lr;
        const _Float16* wrow = Wt + (size_t)col * K + lk;
        f32x4 acc = {0.f, 0.f, 0.f, 0.f};
#pragma unroll
        for (int s = 0; s < 4; ++s) {
            f16x8 b = *(const f16x8*)(wrow + s * 32);
            acc = __builtin_amdgcn_mfma_f32_16x16x32_f16(a[s], b, acc, 0, 0, 0);
        }
        const float bv = BIAS ? bias[col] : 0.f;
#pragma unroll
        for (int j = 0; j < 4; ++j) {
            float o = acc[j] + bv;
            if (OSCALE) o *= os[j];
            Y[(size_t)(rbase + j) * C + col] = (_Float16)o;
        }
    }
}

static inline int cdiv(long long a, long long b) { return (int)((a + b - 1) / b); }

extern "C" void kernel_launch(void* const* d_in, const int* in_sizes, int n_in,
                              void* d_out, int out_size, void* d_ws, size_t ws_size,
                              hipStream_t stream) {
    const float* feat = (const float*)d_in[0];
    const float* W0   = (const float*)d_in[1];
    const float* b0   = (const float*)d_in[2];
    const float* W1   = (const float*)d_in[3];
    const float* b1   = (const float*)d_in[4];
    const float* W2   = (const float*)d_in[5];
    const float* b2   = (const float*)d_in[6];
    const int*   src  = (const int*)d_in[7];
    const int*   dst  = (const int*)d_in[8];

    const int N = in_sizes[0] / DK;
    const int E = in_sizes[7];

    // ws (4B units): nsrc[N] ndst[N] rp[N+1] bin_cnt[512] bin_base[512]
    //                bin_cur[512] eidx[E] | xbuf(fp16 N*128) abuf(fp16 N*128)
    //                Wt0/Wt1/Wt2 (fp16)
    // aliases: binbuf (uint2, E) -> xbuf region (dead before cvt_scale)
    //          srcbuf (int, E)   -> abuf region (dead before gather0 writes)
    float* ws       = (float*)d_ws;
    float* nsrc     = ws;
    float* ndst     = ws + N;
    int*   rp       = (int*)(ws + 2 * (size_t)N);
    int*   bin_cnt  = rp + (N + 1);
    int*   bin_base = bin_cnt + 2 * NBINS_MAX;
    int*   bin_cur  = bin_base + 2 * NBINS_MAX;
    int*   eidx     = bin_cur + 2 * NBINS_MAX;
    size_t aoff     = (size_t)(3 * (size_t)N + 1 + 6 * NBINS_MAX + E + 3) & ~(size_t)3;
    _Float16* xbuf  = (_Float16*)(ws + aoff);                    // N*128 fp16
    _Float16* abuf  = (_Float16*)(ws + aoff + (size_t)N * 64);   // N*128 fp16
    _Float16* Wt0   = (_Float16*)(ws + aoff + (size_t)N * 128);
    _Float16* Wt1   = Wt0 + 128 * 128;
    _Float16* Wt2   = Wt1 + 128 * 128;
    uint2* binbuf   = (uint2*)xbuf;
    int*   srcbuf   = (int*)abuf;

    const int NBINS_USED = cdiv(N, BIN_SIZE);

    // ---- CSR + norms build (no global per-node atomics anywhere) ----
    hipMemsetAsync(bin_cnt, 0, 2 * NBINS_MAX * sizeof(int), stream);
    p1_count<<<256, 256, 0, stream>>>(src, dst, bin_cnt, E);
    p2_scan<<<1, 256, 0, stream>>>(bin_cnt, bin_base, bin_cur);
    p3_scatter<<<cdiv(E, P3_CHUNK), 256, 0, stream>>>(src, dst, bin_cur, binbuf, srcbuf, E);
    p4_finalize<<<NBINS_USED, 256, 0, stream>>>(binbuf, bin_base, bin_cnt, rp, ndst, eidx, N);
    p4b_nsrc<<<NBINS_USED, 256, 0, stream>>>(srcbuf, bin_base, bin_cnt, nsrc, N);

    // ---- weight convert+transpose (fp16), one launch ----
    wcvt_all<<<160, 256, 0, stream>>>(W0, W1, W2, Wt0, Wt1, Wt2);

    const int gat128 = cdiv(N, 16);
    const int gat64  = cdiv(N, 32);
    const int gemm_blocks = cdiv(N, 64);

    // ---- layer 0 ----
    cvt_scale_kernel<<<cdiv((long long)N * 16, 256), 256, 0, stream>>>(feat, nsrc, xbuf, N * 16);
    spmm_gather16<128, false><<<gat128, 256, 0, stream>>>(xbuf, eidx, rp, ndst, nullptr, abuf, N);
    mfma_gemm<128, true, true><<<gemm_blocks, 256, 0, stream>>>(abuf, Wt0, b0, nsrc, xbuf, N);

    // ---- layer 1 ----
    spmm_gather16<128, false><<<gat128, 256, 0, stream>>>(xbuf, eidx, rp, ndst, nullptr, abuf, N);
    mfma_gemm<128, false, true><<<gemm_blocks, 256, 0, stream>>>(abuf, Wt1, b1, nullptr, xbuf, N);

    // ---- layer 2 ----
    mfma_gemm<64, true, false><<<gemm_blocks, 256, 0, stream>>>(xbuf, Wt2, nullptr, nsrc, abuf, N);
    spmm_gather16<64, true><<<gat64, 256, 0, stream>>>(abuf, eidx, rp, ndst, b2, d_out, N);
}